// Round 6
// baseline (132.216 us; speedup 1.0000x reference)
//
#include <hip/hip_runtime.h>

// inputs (256,128,64) f32, mask (256,128) i32, qparams (4,2,10) f32,
// W (4,256,10) f32, b (4,256) f32.
// out f32: outputs(256,128,256) ++ hx(128,256) ++ cx(128,256).
#define T_LEN 256
#define BATCH 128
#define NQ 10
#define HID 256
#define OUT_HX (T_LEN * BATCH * HID)
#define OUT_CX (OUT_HX + BATCH * HID)
#define TCOL 260     // tlds t-dim stride (260 mod 32 = 4; 1040B rows, 16B-aligned)

#define KS  (-1.44269504089f)   // -log2(e): sigmoid scale
#define KT2 (-2.88539008178f)   // -2*log2(e): tanh scale

// ---------------- K1: circuit z precompute ----------------
// One thread per (t,g). Math identical to the validated analytic DP.
// Gate exp2-scale folded into z (sigmoid gates *KS, tanh gate *KT2).
// Layout zws[b][n][t][g] (float4 over g): byte-linear writes, coalesced reads.
__global__ __launch_bounds__(256) void zker(
    const float* __restrict__ inputs,
    const float* __restrict__ qparams,
    float* __restrict__ zws)
{
  const int b   = blockIdx.x;
  const int tq  = blockIdx.y;
  const int tid = threadIdx.x;
  const int t   = tq * 64 + (tid >> 2);
  const int g   = tid & 3;

  const float sg = (g == 2) ? KT2 : KS;

  float th0[NQ], cth[NQ], sth[NQ];
#pragma unroll
  for (int k = 0; k < NQ; ++k) {
    th0[k]   = qparams[g * 2 * NQ + k];
    float t1 = qparams[g * 2 * NQ + NQ + k];
    sth[k] = __sinf(t1);
    cth[k] = __cosf(t1);
  }
  float cphi[NQ], sphi[NQ];
  const float* xp = inputs + (t * BATCH + b) * 64;
#pragma unroll
  for (int k = 0; k < NQ; ++k) {
    float ang = xp[k] + th0[k];
    sphi[k] = __sinf(ang);
    cphi[k] = __cosf(ang);
  }
  float* zout = zws + (b * NQ * T_LEN + t) * 4 + g;   // + w*T_LEN*4 per qubit
#pragma unroll
  for (int w = 0; w < NQ; ++w) {
    float vI, vZ, vY, vX; int js;
    if (w == NQ - 1) { vI = 0.f; vZ = cth[NQ-1]; vY = sth[NQ-1]; vX = 0.f; js = NQ - 2; }
    else             { vI = 1.f; vZ = 0.f; vY = 0.f; vX = 0.f; js = w; }
#pragma unroll
    for (int j = js; j >= 0; --j) {
      float nI = cth[j] * (cphi[j+1] * vZ - sphi[j+1] * vY);
      float nZ = cth[j] * vI;
      float nY = sth[j] * vX;
      float nX = -sth[j] * (sphi[j+1] * vZ + cphi[j+1] * vY);
      vI = nI; vZ = nZ; vY = nY; vX = nX;
    }
    zout[w * T_LEN * 4] = (vI + cphi[0] * vZ - sphi[0] * vY) * sg;
  }
}

// ---------------- K2: 4-t-per-lane blocked parallel scan ----------------
// Pipe model (R4/R5 post-mortem): runtime ~= DS-pipe total + VALU total; the
// 64-lane-per-t scan spent ~25us in per-CU DS throughput (192 bpermutes/wave
// per 256 t). This version: lane owns t=4l..4l+3, composes its 4 affine ops
// locally (VALU), scans 64 composites once (44+4 bpermutes total), expands
// locally. DS/wave drops ~4x -> ~6us chip-wide; one barrier total.
// Block = (b, 32-h group), 8 waves x 4 h each; grid 1024 blocks.
#define BP(SRC, V) __int_as_float(__builtin_amdgcn_ds_bpermute((SRC), __float_as_int(V)))

__global__ __launch_bounds__(512) void scanker(
    const float* __restrict__ zws,
    const int*  __restrict__ mask,
    const float* __restrict__ W,
    const float* __restrict__ bias,
    float* __restrict__ out)
{
  const int b    = blockIdx.x;      // 0..127
  const int h0   = blockIdx.y * 32; // h-group base (8 groups)
  const int tid  = threadIdx.x;     // 0..511
  const int lane = tid & 63;
  const int wavu = __builtin_amdgcn_readfirstlane(tid >> 6);  // provably uniform

  __shared__ float tlds[32][TCOL];  // [hcol][t], 33280 B
  __shared__ float mk[T_LEN];       // 1024 B

  for (int t = tid; t < T_LEN; t += 512) mk[t] = (float)mask[t * BATCH + b];
  __syncthreads();

  // bpermute byte-addrs for the 6-level scan + exclusive shift
  int srcA[6]; bool pm[6];
#pragma unroll
  for (int k = 0; k < 6; ++k) {
    const int d = 1 << k;
    pm[k]   = (lane >= d);
    srcA[k] = ((lane >= d) ? (lane - d) : lane) << 2;
  }
  const int srcE = ((lane >= 1) ? (lane - 1) : 0) << 2;
  const bool pe  = (lane >= 1);

  // hoisted scaled biases (wave-uniform -> SGPRs)
  float bsc[4][4];
#pragma unroll
  for (int hh = 0; hh < 4; ++hh) {
    const int h = __builtin_amdgcn_readfirstlane(h0 + wavu * 4 + hh);
    bsc[hh][0] = bias[0 * HID + h] * KS;
    bsc[hh][1] = bias[1 * HID + h] * KS;
    bsc[hh][2] = bias[2 * HID + h] * KT2;
    bsc[hh][3] = bias[3 * HID + h] * KS;
  }

  const float4* zg = (const float4*)zws + b * NQ * T_LEN;

  // ---- gate phase: a,w,om for lane's 4 t x 4 h ----
  float a[4][4], w[4][4], om[4][4];   // [tt][hh], fully unrolled -> registers
#pragma unroll
  for (int tt = 0; tt < 4; ++tt) {
    const int t = lane * 4 + tt;
    float acc[4][4];                  // [hh][g]
#pragma unroll
    for (int hh = 0; hh < 4; ++hh) {
      acc[hh][0] = bsc[hh][0]; acc[hh][1] = bsc[hh][1];
      acc[hh][2] = bsc[hh][2]; acc[hh][3] = bsc[hh][3];
    }
#pragma unroll
    for (int n = 0; n < NQ; ++n) {
      const float4 z = zg[n * T_LEN + t];
#pragma unroll
      for (int hh = 0; hh < 4; ++hh) {
        const int wb = __builtin_amdgcn_readfirstlane((h0 + wavu * 4 + hh) * NQ + n);
        acc[hh][0] = fmaf(z.x, W[0 * HID * NQ + wb], acc[hh][0]);
        acc[hh][1] = fmaf(z.y, W[1 * HID * NQ + wb], acc[hh][1]);
        acc[hh][2] = fmaf(z.z, W[2 * HID * NQ + wb], acc[hh][2]);
        acc[hh][3] = fmaf(z.w, W[3 * HID * NQ + wb], acc[hh][3]);
      }
    }
    const float m = mk[t];
    const float onem = 1.f - m;
#pragma unroll
    for (int hh = 0; hh < 4; ++hh) {
      const float uf = __builtin_amdgcn_rcpf(1.f + __builtin_amdgcn_exp2f(acc[hh][0]));
      const float ui = __builtin_amdgcn_rcpf(1.f + __builtin_amdgcn_exp2f(acc[hh][1]));
      const float ug = __builtin_amdgcn_rcpf(1.f + __builtin_amdgcn_exp2f(acc[hh][2]));
      const float uo = __builtin_amdgcn_rcpf(1.f + __builtin_amdgcn_exp2f(acc[hh][3]));
      a[tt][hh]  = fmaf(m, uf, onem);                 // decay a_t
      w[tt][hh]  = m * ui * fmaf(2.f, ug, -1.f);      // input w_t (m*m==m)
      om[tt][hh] = fmaf(m, uo, onem);
    }
  }

  // ---- local compose: lane's block composite (A, Wc) ----
  // (a2,w2)o(a1,w1) = (a2*a1, a2*w1 + w2); sequential over tt=0..3
  float A[4], Wc[4];
#pragma unroll
  for (int hh = 0; hh < 4; ++hh) {
    A[hh]  = a[0][hh];
    Wc[hh] = w[0][hh];
#pragma unroll
    for (int tt = 1; tt < 4; ++tt) {
      Wc[hh] = fmaf(a[tt][hh], Wc[hh], w[tt][hh]);
      A[hh]  = a[tt][hh] * A[hh];
    }
  }

  // ---- 6-level Hillis-Steele inclusive scan over lane composites ----
  // (last level skips the A update: A unused afterwards)
#pragma unroll
  for (int k = 0; k < 6; ++k) {
#pragma unroll
    for (int hh = 0; hh < 4; ++hh) {
      float wu = BP(srcA[k], Wc[hh]);
      wu = pm[k] ? wu : 0.f;
      if (k < 5) {
        float au = BP(srcA[k], A[hh]);
        au = pm[k] ? au : 1.f;
        Wc[hh] = fmaf(A[hh], wu, Wc[hh]);
        A[hh]  = A[hh] * au;
      } else {
        Wc[hh] = fmaf(A[hh], wu, Wc[hh]);
      }
    }
  }

  // ---- exclusive prefix: c before this lane's block (c0 = 0 -> just W part) ----
  float cpre[4];
#pragma unroll
  for (int hh = 0; hh < 4; ++hh) {
    const float pw = BP(srcE, Wc[hh]);
    cpre[hh] = pe ? pw : 0.f;
  }

  // ---- per-element expand: c_t, h_t; write [hcol][t] b128 ----
#pragma unroll
  for (int hh = 0; hh < 4; ++hh) {
    float c = cpre[hh];
    float4 hv4;
    float hvs[4];
#pragma unroll
    for (int tt = 0; tt < 4; ++tt) {
      c = fmaf(a[tt][hh], c, w[tt][hh]);
      const float ec = __builtin_amdgcn_exp2f(c * KT2);
      const float tc = fmaf(2.f, __builtin_amdgcn_rcpf(1.f + ec), -1.f);
      hvs[tt] = om[tt][hh] * tc;
    }
    hv4.x = hvs[0]; hv4.y = hvs[1]; hv4.z = hvs[2]; hv4.w = hvs[3];
    const int hcol = wavu * 4 + hh;
    *(float4*)&tlds[hcol][lane * 4] = hv4;    // 16B contiguous, conflict-free
    if (lane == 63) {
      out[OUT_HX + b * HID + h0 + hcol] = hvs[3];
      out[OUT_CX + b * HID + h0 + hcol] = c;
    }
  }

  __syncthreads();

  // ---- transposed writeout: thread q -> (t = q>>1, 16-h half) ----
  {
    const int t  = tid >> 1;
    const int hf = (tid & 1) * 16;
    float v[16];
#pragma unroll
    for (int i = 0; i < 16; ++i) v[i] = tlds[hf + i][t];   // 2-way (free)
    float4* op = (float4*)&out[t * (BATCH * HID) + b * HID + h0 + hf];
    op[0] = make_float4(v[0],  v[1],  v[2],  v[3]);
    op[1] = make_float4(v[4],  v[5],  v[6],  v[7]);
    op[2] = make_float4(v[8],  v[9],  v[10], v[11]);
    op[3] = make_float4(v[12], v[13], v[14], v[15]);
  }
}

extern "C" void kernel_launch(void* const* d_in, const int* in_sizes, int n_in,
                              void* d_out, int out_size, void* d_ws, size_t ws_size,
                              hipStream_t stream)
{
  // identify arrays by unique element counts (order-proof)
  int ii = 0, im = 1, iq = 2, iw = 3, ib = 4;
  for (int i = 0; i < n_in; ++i) {
    switch (in_sizes[i]) {
      case 2097152: ii = i; break;   // inputs (256,128,64)
      case 32768:   im = i; break;   // mask (256,128)
      case 80:      iq = i; break;   // qparams (4,2,10)
      case 10240:   iw = i; break;   // W (4,256,10)
      case 1024:    ib = i; break;   // b (4,256)
      default: break;
    }
  }
  const float* inputs  = (const float*)d_in[ii];
  const int*   mask    = (const int*)d_in[im];
  const float* qparams = (const float*)d_in[iq];
  const float* W       = (const float*)d_in[iw];
  const float* bias    = (const float*)d_in[ib];
  float*       out     = (float*)d_out;
  float*       zws     = (float*)d_ws;   // needs 128*10*256*4*4 = 5.25 MB

  zker<<<dim3(BATCH, 4), dim3(256), 0, stream>>>(inputs, qparams, zws);
  scanker<<<dim3(BATCH, 8), dim3(512), 0, stream>>>(zws, mask, W, bias, out);
}

// Round 7
// 103.620 us; speedup vs baseline: 1.2760x; 1.2760x over previous
//
#include <hip/hip_runtime.h>

// inputs (256,128,64) f32, mask (256,128) i32, qparams (4,2,10) f32,
// W (4,256,10) f32, b (4,256) f32.
// out f32: outputs(256,128,256) ++ hx(128,256) ++ cx(128,256).
#define T_LEN 256
#define BATCH 128
#define NQ 10
#define HID 256
#define OUT_HX (T_LEN * BATCH * HID)
#define OUT_CX (OUT_HX + BATCH * HID)
#define TROW 33      // [t][h] tile row stride (odd -> conflict-free both phases)

#define KS  (-1.44269504089f)   // -log2(e): sigmoid scale
#define KT2 (-2.88539008178f)   // -2*log2(e): tanh scale

// ---------------- K1: circuit z precompute ----------------
// One thread per (t,g). Math identical to the validated analytic DP.
// Gate exp2-scale folded into z (sigmoid gates *KS, tanh gate *KT2).
// Layout zws[b][n][t][g] (float4 over g): byte-linear writes; scanker reads
// (t = r*64+lane) are 1KB-contiguous per (n, wave) -> perfectly coalesced.
__global__ __launch_bounds__(256) void zker(
    const float* __restrict__ inputs,
    const float* __restrict__ qparams,
    float* __restrict__ zws)
{
  const int b   = blockIdx.x;
  const int tq  = blockIdx.y;
  const int tid = threadIdx.x;
  const int t   = tq * 64 + (tid >> 2);
  const int g   = tid & 3;

  const float sg = (g == 2) ? KT2 : KS;

  float th0[NQ], cth[NQ], sth[NQ];
#pragma unroll
  for (int k = 0; k < NQ; ++k) {
    th0[k]   = qparams[g * 2 * NQ + k];
    float t1 = qparams[g * 2 * NQ + NQ + k];
    sth[k] = __sinf(t1);
    cth[k] = __cosf(t1);
  }
  float cphi[NQ], sphi[NQ];
  const float* xp = inputs + (t * BATCH + b) * 64;
#pragma unroll
  for (int k = 0; k < NQ; ++k) {
    float ang = xp[k] + th0[k];
    sphi[k] = __sinf(ang);
    cphi[k] = __cosf(ang);
  }
  float* zout = zws + (b * NQ * T_LEN + t) * 4 + g;   // + w*T_LEN*4 per qubit
#pragma unroll
  for (int w = 0; w < NQ; ++w) {
    float vI, vZ, vY, vX; int js;
    if (w == NQ - 1) { vI = 0.f; vZ = cth[NQ-1]; vY = sth[NQ-1]; vX = 0.f; js = NQ - 2; }
    else             { vI = 1.f; vZ = 0.f; vY = 0.f; vX = 0.f; js = w; }
#pragma unroll
    for (int j = js; j >= 0; --j) {
      float nI = cth[j] * (cphi[j+1] * vZ - sphi[j+1] * vY);
      float nZ = cth[j] * vI;
      float nY = sth[j] * vX;
      float nX = -sth[j] * (sphi[j+1] * vZ + cphi[j+1] * vY);
      vI = nI; vZ = nZ; vY = nY; vX = nX;
    }
    zout[w * T_LEN * 4] = (vI + cphi[0] * vZ - sphi[0] * vY) * sg;
  }
}

// ---------------- K2: parallel-scan LSTM, DPP scan (no DS pipe) ----------------
// R2-R6 post-mortem: every structure serialized barrier-convoyed ds_bpermute
// round-trips (~100cy each, per-CU pipe). This version runs the wave64
// affine scan on DPP (row_shr 1/2/4/8 + row_bcast15/31) - full-rate VALU,
// ~10cy/level chain, zero DS contention. Carry via v_readlane. Structure =
// R5: strided t (coalesced z), 32-h groups, 8 waves x 4h, tlds ping-pong.

// one scan level: compose self with shifted-in prefix (identity old)
#define DPP_STEP(CTRL, RMASK)                                            \
  {                                                                      \
    _Pragma("unroll")                                                    \
    for (int hh = 0; hh < 4; ++hh) {                                     \
      const float Ash = __int_as_float(__builtin_amdgcn_update_dpp(      \
          0x3f800000, __float_as_int(A[hh]), CTRL, RMASK, 0xF, false));  \
      const float Wsh = __int_as_float(__builtin_amdgcn_update_dpp(      \
          0, __float_as_int(Wc[hh]), CTRL, RMASK, 0xF, false));          \
      Wc[hh] = fmaf(A[hh], Wsh, Wc[hh]);                                 \
      A[hh]  = A[hh] * Ash;                                              \
    }                                                                    \
  }

__global__ __launch_bounds__(512) void scanker(
    const float* __restrict__ zws,
    const int*  __restrict__ mask,
    const float* __restrict__ W,
    const float* __restrict__ bias,
    float* __restrict__ out)
{
  const int b    = blockIdx.x;      // 0..127
  const int h0   = blockIdx.y * 32; // h-group base (8 groups)
  const int tid  = threadIdx.x;     // 0..511
  const int lane = tid & 63;
  const int wavu = __builtin_amdgcn_readfirstlane(tid >> 6);  // provably uniform

  __shared__ float tlds[2][64 * TROW];  // 2 x 8448 B (ping-pong)
  __shared__ float mk[T_LEN];           // 1024 B

  for (int t = tid; t < T_LEN; t += 512) mk[t] = (float)mask[t * BATCH + b];
  __syncthreads();

  // hoisted scaled biases (wave-uniform -> SGPRs)
  float bsc[4][4];
#pragma unroll
  for (int hh = 0; hh < 4; ++hh) {
    const int h = __builtin_amdgcn_readfirstlane(h0 + wavu * 4 + hh);
    bsc[hh][0] = bias[0 * HID + h] * KS;
    bsc[hh][1] = bias[1 * HID + h] * KS;
    bsc[hh][2] = bias[2 * HID + h] * KT2;
    bsc[hh][3] = bias[3 * HID + h] * KS;
  }

  float carry[4];
#pragma unroll
  for (int i = 0; i < 4; ++i) carry[i] = 0.f;

  const float4* zg = (const float4*)zws + b * NQ * T_LEN;

  for (int r = 0; r < 4; ++r) {
    const int p = r & 1;
    const int t = r * 64 + lane;
    const float m = mk[t];
    const float onem = 1.f - m;

    // ---- gate phase, n-chunked: one z float4 feeds 16 accumulators ----
    float acc[4][4];
#pragma unroll
    for (int hh = 0; hh < 4; ++hh) {
      acc[hh][0] = bsc[hh][0]; acc[hh][1] = bsc[hh][1];
      acc[hh][2] = bsc[hh][2]; acc[hh][3] = bsc[hh][3];
    }
#pragma unroll
    for (int n = 0; n < NQ; ++n) {
      const float4 z = zg[n * T_LEN + t];   // coalesced, L2-served
#pragma unroll
      for (int hh = 0; hh < 4; ++hh) {
        const int wb = __builtin_amdgcn_readfirstlane((h0 + wavu * 4 + hh) * NQ + n);
        acc[hh][0] = fmaf(z.x, W[0 * HID * NQ + wb], acc[hh][0]);
        acc[hh][1] = fmaf(z.y, W[1 * HID * NQ + wb], acc[hh][1]);
        acc[hh][2] = fmaf(z.z, W[2 * HID * NQ + wb], acc[hh][2]);
        acc[hh][3] = fmaf(z.w, W[3 * HID * NQ + wb], acc[hh][3]);
      }
    }

    float A[4], Wc[4], om4[4];
#pragma unroll
    for (int hh = 0; hh < 4; ++hh) {
      const float uf = __builtin_amdgcn_rcpf(1.f + __builtin_amdgcn_exp2f(acc[hh][0]));
      const float ui = __builtin_amdgcn_rcpf(1.f + __builtin_amdgcn_exp2f(acc[hh][1]));
      const float ug = __builtin_amdgcn_rcpf(1.f + __builtin_amdgcn_exp2f(acc[hh][2]));
      const float uo = __builtin_amdgcn_rcpf(1.f + __builtin_amdgcn_exp2f(acc[hh][3]));
      A[hh]   = fmaf(m, uf, onem);                 // decay a_t
      Wc[hh]  = m * ui * fmaf(2.f, ug, -1.f);      // input w_t (m*m==m)
      om4[hh] = fmaf(m, uo, onem);
    }

    // ---- wave64 inclusive affine scan on DPP (rocPRIM pattern) ----
    DPP_STEP(0x111, 0xF)   // row_shr:1
    DPP_STEP(0x112, 0xF)   // row_shr:2
    DPP_STEP(0x114, 0xF)   // row_shr:4
    DPP_STEP(0x118, 0xF)   // row_shr:8
    DPP_STEP(0x142, 0xA)   // row_bcast:15 into rows 1,3
    DPP_STEP(0x143, 0xC)   // row_bcast:31 into rows 2,3

    // ---- carry, tanh, store ----
#pragma unroll
    for (int hh = 0; hh < 4; ++hh) {
      const float ct = fmaf(A[hh], carry[hh], Wc[hh]);
      carry[hh] = __int_as_float(
          __builtin_amdgcn_readlane(__float_as_int(ct), 63));  // SALU bcast
      const float ec = __builtin_amdgcn_exp2f(ct * KT2);
      const float tc = fmaf(2.f, __builtin_amdgcn_rcpf(1.f + ec), -1.f);
      const float hv = om4[hh] * tc;
      tlds[p][lane * TROW + wavu * 4 + hh] = hv;
      if (r == 3 && lane == 63) {
        const int h = h0 + wavu * 4 + hh;
        out[OUT_HX + b * HID + h] = hv;
        out[OUT_CX + b * HID + h] = ct;
      }
    }

    __syncthreads();   // tlds[p] complete; ping-pong needs only this barrier
    // coalesced writeout: 64 t x 32 h tile, 128B contiguous per t
    {
      const int tt = tid >> 3, c = tid & 7;   // 64 t x 8 float4-cols
      float4 v;
      v.x = tlds[p][tt * TROW + 4 * c + 0];
      v.y = tlds[p][tt * TROW + 4 * c + 1];
      v.z = tlds[p][tt * TROW + 4 * c + 2];
      v.w = tlds[p][tt * TROW + 4 * c + 3];
      *(float4*)&out[(r * 64 + tt) * (BATCH * HID) + b * HID + h0 + 4 * c] = v;
    }
    // no second barrier: next round writes tlds[1-p], whose readers passed
    // this barrier already
  }
}

extern "C" void kernel_launch(void* const* d_in, const int* in_sizes, int n_in,
                              void* d_out, int out_size, void* d_ws, size_t ws_size,
                              hipStream_t stream)
{
  // identify arrays by unique element counts (order-proof)
  int ii = 0, im = 1, iq = 2, iw = 3, ib = 4;
  for (int i = 0; i < n_in; ++i) {
    switch (in_sizes[i]) {
      case 2097152: ii = i; break;   // inputs (256,128,64)
      case 32768:   im = i; break;   // mask (256,128)
      case 80:      iq = i; break;   // qparams (4,2,10)
      case 10240:   iw = i; break;   // W (4,256,10)
      case 1024:    ib = i; break;   // b (4,256)
      default: break;
    }
  }
  const float* inputs  = (const float*)d_in[ii];
  const int*   mask    = (const int*)d_in[im];
  const float* qparams = (const float*)d_in[iq];
  const float* W       = (const float*)d_in[iw];
  const float* bias    = (const float*)d_in[ib];
  float*       out     = (float*)d_out;
  float*       zws     = (float*)d_ws;   // needs 128*10*256*4*4 = 5.25 MB

  zker<<<dim3(BATCH, 4), dim3(256), 0, stream>>>(inputs, qparams, zws);
  scanker<<<dim3(BATCH, 8), dim3(512), 0, stream>>>(zws, mask, W, bias, out);
}